// Round 7
// baseline (38.862 us; speedup 1.0000x reference)
//
#include <hip/hip_runtime.h>

// SSIM map: refl-pad(1) + 3x3 avg-pool stencil, B=16 C=3 H=512 W=512 fp32.
// R6 post-mortem: f4 restructure regressed -> revert to R5 scalar sliding
// window (34.3us). R7 levers: (1) nontemporal output stores so the 49MB
// write stream doesn't evict the L3-resident inputs (FETCH was 58MB/replay
// despite 100MB inputs < 256MB L3); (2) ROWS 32->16 for 2x blocks.

#define HH 512
#define WW 512
#define ROWS 16          // rows per thread; grid.y = HH/ROWS
#define SSIM_C1 1e-4f    // 0.01^2
#define SSIM_C2 9e-4f    // 0.03^2

__global__ __launch_bounds__(256) void ssim_kernel(const float* __restrict__ x,
                                                   const float* __restrict__ y,
                                                   float* __restrict__ out) {
    const int col   = blockIdx.x * 256 + threadIdx.x;   // 0..511
    const int row0  = blockIdx.y * ROWS;
    const size_t po = (size_t)blockIdx.z * (size_t)(HH * WW);
    const float* xp = x + po;
    const float* yp = y + po;
    float* op       = out + po;

    // reflection-pad(1) column neighbors
    const int cl = (col == 0)      ? 1      : col - 1;
    const int cr = (col == WW - 1) ? WW - 2 : col + 1;

    // 3-deep sliding window of horizontal row-sums for 5 quantities.
    float sx0, sy0, sxx0, syy0, sxy0;
    float sx1, sy1, sxx1, syy1, sxy1;
    float sx2, sy2, sxx2, syy2, sxy2;

#define LOADROW(r, SX, SY, SXX, SYY, SXY) do {                      \
    int rr_ = (r) < 0 ? 1 : ((r) >= HH ? HH - 2 : (r));             \
    const float* xr_ = xp + rr_ * WW;                               \
    const float* yr_ = yp + rr_ * WW;                               \
    float xl_ = xr_[cl], xc_ = xr_[col], xv_ = xr_[cr];             \
    float yl_ = yr_[cl], yc_ = yr_[col], yv_ = yr_[cr];             \
    SX  = xl_ + xc_ + xv_;                                          \
    SY  = yl_ + yc_ + yv_;                                          \
    SXX = xl_*xl_ + xc_*xc_ + xv_*xv_;                              \
    SYY = yl_*yl_ + yc_*yc_ + yv_*yv_;                              \
    SXY = xl_*yl_ + xc_*yc_ + xv_*yv_;                              \
} while (0)

    // Prime rows row0-1 (reflected) and row0.
    LOADROW(row0 - 1, sx0, sy0, sxx0, syy0, sxy0);
    LOADROW(row0,     sx1, sy1, sxx1, syy1, sxy1);

    const float inv9 = 1.0f / 9.0f;

    #pragma unroll 4
    for (int i = 0; i < ROWS; ++i) {
        const int r = row0 + i;
        LOADROW(r + 1, sx2, sy2, sxx2, syy2, sxy2);

        const float sx  = sx0  + sx1  + sx2;
        const float sy  = sy0  + sy1  + sy2;
        const float sxx = sxx0 + sxx1 + sxx2;
        const float syy = syy0 + syy1 + syy2;
        const float sxy = sxy0 + sxy1 + sxy2;

        const float mux   = sx * inv9;
        const float muy   = sy * inv9;
        const float sigx  = sxx * inv9 - mux * mux;
        const float sigy  = syy * inv9 - muy * muy;
        const float sigxy = sxy * inv9 - mux * muy;

        const float n = (2.0f * mux * muy + SSIM_C1) * (2.0f * sigxy + SSIM_C2);
        const float d = (mux * mux + muy * muy + SSIM_C1) * (sigx + sigy + SSIM_C2);
        float v = (1.0f - n / (d + 1e-8f)) * 0.5f;
        v = fminf(fmaxf(v, 0.0f), 1.0f);

        // nontemporal: output is never re-read; don't let the 49MB write
        // stream evict the L3-resident inputs across graph replays.
        __builtin_nontemporal_store(v, op + (size_t)r * WW + col);

        // slide window down one row (scalar shift -> SSA-renamed, no scratch)
        sx0 = sx1;  sy0 = sy1;  sxx0 = sxx1;  syy0 = syy1;  sxy0 = sxy1;
        sx1 = sx2;  sy1 = sy2;  sxx1 = sxx2;  syy1 = syy2;  sxy1 = sxy2;
    }
#undef LOADROW
}

extern "C" void kernel_launch(void* const* d_in, const int* in_sizes, int n_in,
                              void* d_out, int out_size, void* d_ws, size_t ws_size,
                              hipStream_t stream) {
    const float* x = (const float*)d_in[0];
    const float* y = (const float*)d_in[1];
    float* out     = (float*)d_out;

    // B*C = 48 planes of 512x512
    dim3 block(256, 1, 1);
    dim3 grid(WW / 256, HH / ROWS, 48);   // (2, 32, 48) = 3072 blocks
    ssim_kernel<<<grid, block, 0, stream>>>(x, y, out);
}

// Round 8
// 33.611 us; speedup vs baseline: 1.1563x; 1.1563x over previous
//
#include <hip/hip_runtime.h>

// SSIM map: refl-pad(1) + 3x3 avg-pool stencil, B=16 C=3 H=512 W=512 fp32.
// R7 post-mortem: NT store falsified (FETCH unchanged, replay slower) ->
// plain stores. Keep ROWS=16 (occupancy 47->54%). New lever: software
// pipeline depth-2 — issue row r+2's 6 loads before consuming row r+1's,
// double-buffered in named scalars (A/B) so ~12 loads stay in flight.

#define HH 512
#define WW 512
#define ROWS 16          // rows per thread; grid.y = HH/ROWS
#define SSIM_C1 1e-4f    // 0.01^2
#define SSIM_C2 9e-4f    // 0.03^2

__global__ __launch_bounds__(256) void ssim_kernel(const float* __restrict__ x,
                                                   const float* __restrict__ y,
                                                   float* __restrict__ out) {
    const int col   = blockIdx.x * 256 + threadIdx.x;   // 0..511
    const int row0  = blockIdx.y * ROWS;
    const size_t po = (size_t)blockIdx.z * (size_t)(HH * WW);
    const float* xp = x + po;
    const float* yp = y + po;
    float* op       = out + po;

    // reflection-pad(1) column neighbors
    const int cl = (col == 0)      ? 1      : col - 1;
    const int cr = (col == WW - 1) ? WW - 2 : col + 1;

    const float inv9 = 1.0f / 9.0f;

    // raw load buffers A and B (6 floats each), explicitly named
    float Axl, Axc, Axr, Ayl, Ayc, Ayr;
    float Bxl, Bxc, Bxr, Byl, Byc, Byr;

#define ISSUE(r, XL, XC, XR, YL, YC, YR) do {                       \
    int rr_ = (r) < 0 ? 1 : ((r) >= HH ? HH - 2 : (r));             \
    const float* xr_ = xp + rr_ * WW;                               \
    const float* yr_ = yp + rr_ * WW;                               \
    XL = xr_[cl]; XC = xr_[col]; XR = xr_[cr];                      \
    YL = yr_[cl]; YC = yr_[col]; YR = yr_[cr];                      \
} while (0)

#define HSUM(XL, XC, XR, YL, YC, YR, SX, SY, SXX, SYY, SXY) do {    \
    SX  = XL + XC + XR;                                             \
    SY  = YL + YC + YR;                                             \
    SXX = XL*XL + XC*XC + XR*XR;                                    \
    SYY = YL*YL + YC*YC + YR*YR;                                    \
    SXY = XL*YL + XC*YC + XR*YR;                                    \
} while (0)

#define EMIT(r, SX2, SY2, SXX2, SYY2, SXY2) do {                            \
    const float sx  = sx0  + sx1  + (SX2);                                  \
    const float sy  = sy0  + sy1  + (SY2);                                  \
    const float sxx = sxx0 + sxx1 + (SXX2);                                 \
    const float syy = syy0 + syy1 + (SYY2);                                 \
    const float sxy = sxy0 + sxy1 + (SXY2);                                 \
    const float mux   = sx * inv9;                                          \
    const float muy   = sy * inv9;                                          \
    const float sigx  = sxx * inv9 - mux * mux;                             \
    const float sigy  = syy * inv9 - muy * muy;                             \
    const float sigxy = sxy * inv9 - mux * muy;                             \
    const float n = (2.0f * mux * muy + SSIM_C1) * (2.0f * sigxy + SSIM_C2);\
    const float d = (mux*mux + muy*muy + SSIM_C1) * (sigx + sigy + SSIM_C2);\
    float v = (1.0f - n / (d + 1e-8f)) * 0.5f;                              \
    v = fminf(fmaxf(v, 0.0f), 1.0f);                                        \
    op[(size_t)(r) * WW + col] = v;                                         \
    sx0 = sx1;  sy0 = sy1;  sxx0 = sxx1;  syy0 = syy1;  sxy0 = sxy1;        \
    sx1 = SX2;  sy1 = SY2;  sxx1 = SXX2;  syy1 = SYY2;  sxy1 = SXY2;        \
} while (0)

    // ---- prologue: prime 2-row window + first in-flight row ----
    float sx0, sy0, sxx0, syy0, sxy0;
    float sx1, sy1, sxx1, syy1, sxy1;
    float sx2, sy2, sxx2, syy2, sxy2;

    ISSUE(row0 - 1, Axl, Axc, Axr, Ayl, Ayc, Ayr);
    ISSUE(row0,     Bxl, Bxc, Bxr, Byl, Byc, Byr);
    HSUM(Axl, Axc, Axr, Ayl, Ayc, Ayr, sx0, sy0, sxx0, syy0, sxy0);
    HSUM(Bxl, Bxc, Bxr, Byl, Byc, Byr, sx1, sy1, sxx1, syy1, sxy1);
    ISSUE(row0 + 1, Axl, Axc, Axr, Ayl, Ayc, Ayr);   // row r+1 in flight in A

    // ---- steady state: 2 rows per trip; loads issued one row ahead ----
    #pragma unroll 2
    for (int i = 0; i < ROWS; i += 2) {
        const int r = row0 + i;

        // consume A (row r+1), issue B (row r+2)
        ISSUE(r + 2, Bxl, Bxc, Bxr, Byl, Byc, Byr);
        HSUM(Axl, Axc, Axr, Ayl, Ayc, Ayr, sx2, sy2, sxx2, syy2, sxy2);
        EMIT(r, sx2, sy2, sxx2, syy2, sxy2);

        // consume B (row r+2), issue A (row r+3)
        ISSUE(r + 3, Axl, Axc, Axr, Ayl, Ayc, Ayr);
        HSUM(Bxl, Bxc, Bxr, Byl, Byc, Byr, sx2, sy2, sxx2, syy2, sxy2);
        EMIT(r + 1, sx2, sy2, sxx2, syy2, sxy2);
    }
#undef ISSUE
#undef HSUM
#undef EMIT
}

extern "C" void kernel_launch(void* const* d_in, const int* in_sizes, int n_in,
                              void* d_out, int out_size, void* d_ws, size_t ws_size,
                              hipStream_t stream) {
    const float* x = (const float*)d_in[0];
    const float* y = (const float*)d_in[1];
    float* out     = (float*)d_out;

    // B*C = 48 planes of 512x512
    dim3 block(256, 1, 1);
    dim3 grid(WW / 256, HH / ROWS, 48);   // (2, 32, 48) = 3072 blocks
    ssim_kernel<<<grid, block, 0, stream>>>(x, y, out);
}

// Round 9
// 33.489 us; speedup vs baseline: 1.1605x; 1.0036x over previous
//
#include <hip/hip_runtime.h>

// SSIM map: refl-pad(1) + 3x3 avg-pool stencil, B=16 C=3 H=512 W=512 fp32.
// Ledger: R5 scalar 34.3us | R6 float4 36.8 (occ 35%) | R7 NT-store 38.9
// (falsified) | R8 sw-pipeline 33.6 (VGPR stayed 32 - compiler sank loads).
// R9 theory: latency-bound, per-wave MLP ~1 row. Fix: TWO independent
// z-plane chains per thread -> 12 independent loads/row the scheduler must
// interleave; grid (2,32,24)=1536 blocks = exactly 6 blocks/CU, one
// residency round, no tail.

#define HH 512
#define WW 512
#define ROWS 16          // rows per thread
#define NZ 24            // grid.z; thread handles planes z and z+NZ
#define SSIM_C1 1e-4f    // 0.01^2
#define SSIM_C2 9e-4f    // 0.03^2

__global__ __launch_bounds__(256, 6) void ssim_kernel(const float* __restrict__ x,
                                                      const float* __restrict__ y,
                                                      float* __restrict__ out) {
    const int col   = blockIdx.x * 256 + threadIdx.x;   // 0..511
    const int row0  = blockIdx.y * ROWS;
    const size_t pA = (size_t)blockIdx.z * (size_t)(HH * WW);
    const size_t pB = (size_t)(blockIdx.z + NZ) * (size_t)(HH * WW);
    const float* xA = x + pA;  const float* yA = y + pA;  float* oA = out + pA;
    const float* xB = x + pB;  const float* yB = y + pB;  float* oB = out + pB;

    // reflection-pad(1) column neighbors
    const int cl = (col == 0)      ? 1      : col - 1;
    const int cr = (col == WW - 1) ? WW - 2 : col + 1;

    const float inv9 = 1.0f / 9.0f;

    // two independent 3-deep sliding windows (planes A and B)
    float Asx0, Asy0, Asxx0, Asyy0, Asxy0;
    float Asx1, Asy1, Asxx1, Asyy1, Asxy1;
    float Bsx0, Bsy0, Bsxx0, Bsyy0, Bsxy0;
    float Bsx1, Bsy1, Bsxx1, Bsyy1, Bsxy1;

// load row r of BOTH planes (12 independent loads), then fold to row-sums
#define LOADROW2(r, ASX, ASY, ASXX, ASYY, ASXY, BSX, BSY, BSXX, BSYY, BSXY) do { \
    int rr_ = (r) < 0 ? 1 : ((r) >= HH ? HH - 2 : (r));             \
    const float* xa_ = xA + rr_ * WW;                               \
    const float* ya_ = yA + rr_ * WW;                               \
    const float* xb_ = xB + rr_ * WW;                               \
    const float* yb_ = yB + rr_ * WW;                               \
    float axl_ = xa_[cl], axc_ = xa_[col], axr_ = xa_[cr];          \
    float ayl_ = ya_[cl], ayc_ = ya_[col], ayr_ = ya_[cr];          \
    float bxl_ = xb_[cl], bxc_ = xb_[col], bxr_ = xb_[cr];          \
    float byl_ = yb_[cl], byc_ = yb_[col], byr_ = yb_[cr];          \
    ASX  = axl_ + axc_ + axr_;                                      \
    ASY  = ayl_ + ayc_ + ayr_;                                      \
    ASXX = axl_*axl_ + axc_*axc_ + axr_*axr_;                       \
    ASYY = ayl_*ayl_ + ayc_*ayc_ + ayr_*ayr_;                       \
    ASXY = axl_*ayl_ + axc_*ayc_ + axr_*ayr_;                       \
    BSX  = bxl_ + bxc_ + bxr_;                                      \
    BSY  = byl_ + byc_ + byr_;                                      \
    BSXX = bxl_*bxl_ + bxc_*bxc_ + bxr_*bxr_;                       \
    BSYY = byl_*byl_ + byc_*byc_ + byr_*byr_;                       \
    BSXY = bxl_*byl_ + bxc_*byc_ + bxr_*byr_;                       \
} while (0)

#define EMIT(OP, r, S0x,S0y,S0xx,S0yy,S0xy, S1x,S1y,S1xx,S1yy,S1xy, S2x,S2y,S2xx,S2yy,S2xy) do { \
    const float sx  = S0x  + S1x  + S2x;                                    \
    const float sy  = S0y  + S1y  + S2y;                                    \
    const float sxx = S0xx + S1xx + S2xx;                                   \
    const float syy = S0yy + S1yy + S2yy;                                   \
    const float sxy = S0xy + S1xy + S2xy;                                   \
    const float mux   = sx * inv9;                                          \
    const float muy   = sy * inv9;                                          \
    const float sigx  = sxx * inv9 - mux * mux;                             \
    const float sigy  = syy * inv9 - muy * muy;                             \
    const float sigxy = sxy * inv9 - mux * muy;                             \
    const float n = (2.0f * mux * muy + SSIM_C1) * (2.0f * sigxy + SSIM_C2);\
    const float d = (mux*mux + muy*muy + SSIM_C1) * (sigx + sigy + SSIM_C2);\
    float v = (1.0f - n / (d + 1e-8f)) * 0.5f;                              \
    v = fminf(fmaxf(v, 0.0f), 1.0f);                                        \
    OP[(size_t)(r) * WW + col] = v;                                         \
} while (0)

    // prime both windows: rows row0-1 (reflected) and row0
    LOADROW2(row0 - 1, Asx0, Asy0, Asxx0, Asyy0, Asxy0,
                       Bsx0, Bsy0, Bsxx0, Bsyy0, Bsxy0);
    LOADROW2(row0,     Asx1, Asy1, Asxx1, Asyy1, Asxy1,
                       Bsx1, Bsy1, Bsxx1, Bsyy1, Bsxy1);

    #pragma unroll 4
    for (int i = 0; i < ROWS; ++i) {
        const int r = row0 + i;
        float Asx2, Asy2, Asxx2, Asyy2, Asxy2;
        float Bsx2, Bsy2, Bsxx2, Bsyy2, Bsxy2;
        LOADROW2(r + 1, Asx2, Asy2, Asxx2, Asyy2, Asxy2,
                        Bsx2, Bsy2, Bsxx2, Bsyy2, Bsxy2);

        EMIT(oA, r, Asx0,Asy0,Asxx0,Asyy0,Asxy0,
                    Asx1,Asy1,Asxx1,Asyy1,Asxy1,
                    Asx2,Asy2,Asxx2,Asyy2,Asxy2);
        EMIT(oB, r, Bsx0,Bsy0,Bsxx0,Bsyy0,Bsxy0,
                    Bsx1,Bsy1,Bsxx1,Bsyy1,Bsxy1,
                    Bsx2,Bsy2,Bsxx2,Bsyy2,Bsxy2);

        // slide both windows (scalar shift, SSA-renamed)
        Asx0 = Asx1; Asy0 = Asy1; Asxx0 = Asxx1; Asyy0 = Asyy1; Asxy0 = Asxy1;
        Asx1 = Asx2; Asy1 = Asy2; Asxx1 = Asxx2; Asyy1 = Asyy2; Asxy1 = Asxy2;
        Bsx0 = Bsx1; Bsy0 = Bsy1; Bsxx0 = Bsxx1; Bsyy0 = Bsyy1; Bsxy0 = Bsxy1;
        Bsx1 = Bsx2; Bsy1 = Bsy2; Bsxx1 = Bsxx2; Bsyy1 = Bsyy2; Bsxy1 = Bsxy2;
    }
#undef LOADROW2
#undef EMIT
}

extern "C" void kernel_launch(void* const* d_in, const int* in_sizes, int n_in,
                              void* d_out, int out_size, void* d_ws, size_t ws_size,
                              hipStream_t stream) {
    const float* x = (const float*)d_in[0];
    const float* y = (const float*)d_in[1];
    float* out     = (float*)d_out;

    // 48 planes; each thread does planes z and z+24 -> grid.z = 24.
    // 1536 blocks = 6 blocks/CU, single residency round, no tail.
    dim3 block(256, 1, 1);
    dim3 grid(WW / 256, HH / ROWS, NZ);   // (2, 32, 24)
    ssim_kernel<<<grid, block, 0, stream>>>(x, y, out);
}